// Round 9
// baseline (192.690 us; speedup 1.0000x reference)
//
#include <hip/hip_runtime.h>
#include <hip/hip_bf16.h>

typedef __attribute__((ext_vector_type(8))) short sh8;     // 8 bf16 (4 VGPRs)
typedef __attribute__((ext_vector_type(4))) float f32x4;   // MFMA C/D

#define LDC 136   // gemm epilogue C-tile stride in shorts
#define QSCALE 0.18033688f   // 0.125 * log2(e): folded into q at GEMM epilogue
#define KMBF16 0xF14Au       // bf16(-1e30): exp2(score-1e30) == 0 exactly

#define EXP2F(x) __builtin_amdgcn_exp2f(x)   // v_exp_f32 (base-2), no libm wrapper

// async global->LDS DMA, 16B/lane; LDS dest = wave-uniform base + lane*16 (m104/m108)
__device__ __forceinline__ void glds16(const unsigned short* g, unsigned short* l){
  __builtin_amdgcn_global_load_lds(
      (const __attribute__((address_space(1))) unsigned int*)g,
      (__attribute__((address_space(3))) unsigned int*)l, 16, 0, 0);
}

__device__ __forceinline__ unsigned short f2bf(float f){
  union { float f; unsigned u; } c; c.f = f;
  unsigned u = c.u;
  u += 0x7fffu + ((u >> 16) & 1u);   // RNE
  return (unsigned short)(u >> 16);
}

__device__ __forceinline__ unsigned long long pack4bf(float a, float b, float c, float d){
  __hip_bfloat162 lo = __float22bfloat162_rn(make_float2(a, b));  // v_cvt_pk_bf16_f32
  __hip_bfloat162 hi = __float22bfloat162_rn(make_float2(c, d));
  union { unsigned u[2]; unsigned long long ull; } pk;
  pk.u[0] = *(unsigned*)&lo; pk.u[1] = *(unsigned*)&hi;
  return pk.ull;
}

// gfx950 cross-lane row swaps (VALU pipe -- no LDS traffic)
// p32: vdst[32:63] <-> vsrc[0:31]   p16: vdst[16:31],[48:63] <-> vsrc[0:15],[32:47]
__device__ __forceinline__ void pl32swap(unsigned &a, unsigned &b){
  asm volatile("v_permlane32_swap_b32 %0, %1" : "+v"(a), "+v"(b));
}
__device__ __forceinline__ void pl16swap(unsigned &a, unsigned &b){
  asm volatile("v_permlane16_swap_b32 %0, %1" : "+v"(a), "+v"(b));
}

// ---------------- fp32 -> bf16 elementwise (x and Wo fused in one launch) ----------------
__global__ __launch_bounds__(256) void cvt_bf16_2(const float* __restrict__ s0,
                                                  unsigned short* __restrict__ d0, int n0,
                                                  const float* __restrict__ s1,
                                                  unsigned short* __restrict__ d1, int n1){
  int i = blockIdx.x*256 + threadIdx.x;
  const float* s; unsigned short* d;
  if (i < n0){ s = s0; d = d0; }
  else if (i < n0 + n1){ s = s1; d = d1; i -= n0; }
  else return;
  float4 v = ((const float4*)s)[i];
  ushort4 o;
  o.x = f2bf(v.x); o.y = f2bf(v.y); o.z = f2bf(v.z); o.w = f2bf(v.w);
  ((ushort4*)d)[i] = o;
}

// ---------------- Wq/Wk/Wv (H,D,DH) -> Wt[j=jm*1024+h*64+e][d] bf16 (B^T layout) ----------------
__global__ __launch_bounds__(256) void transpose_w(const float* __restrict__ Wq,
                                                   const float* __restrict__ Wk,
                                                   const float* __restrict__ Wv,
                                                   unsigned short* __restrict__ wt){
  __shared__ float tile[64][65];
  int idx = blockIdx.x;            // 0..767 = 3 * 16(h) * 16(dt)
  int jm = idx >> 8;
  int rest = idx & 255;
  int h = rest >> 4, dt = rest & 15;
  const float* src = (jm==0 ? Wq : (jm==1 ? Wk : Wv)) + (size_t)h*65536;  // [D][64] slab
  int t = threadIdx.x;
  {
    int r = t >> 2, c0 = (t & 3)*16;
    for (int i=0;i<4;++i){
      float4 v = *(const float4*)&src[(size_t)(dt*64 + r)*64 + c0 + i*4];
      tile[r][c0+i*4+0]=v.x; tile[r][c0+i*4+1]=v.y; tile[r][c0+i*4+2]=v.z; tile[r][c0+i*4+3]=v.w;
    }
  }
  __syncthreads();
  {
    int e = t >> 2, r0 = (t & 3)*16;
    int j = jm*1024 + h*64 + e;
    __align__(16) unsigned short buf[16];
    for (int i=0;i<16;++i) buf[i] = f2bf(tile[r0+i][e]);
    *(uint4*)&wt[(size_t)j*1024 + dt*64 + r0    ] = *(uint4*)&buf[0];
    *(uint4*)&wt[(size_t)j*1024 + dt*64 + r0 + 8] = *(uint4*)&buf[8];
  }
}

// ---------------- GEMM C[M,N] = A[M,K] * Bt[N,K]^T, bf16 in / fp32 acc ----------------
// R7/R8: flash-style single-barrier double-buffered K-loop; same-XCD group swizzle
// (8 m-blocks sharing a B-column land on one XCD L2). Verified: gemm0 70.5 -> <62us.
// mode 0: N=3072 fused QKV -> q (pre-scaled by QSCALE), k [b][h][s][e]; v [b][h][e][s]
// mode 2: N=1024 -> Cf fp32 (final output)
template<int BM>
__global__ __launch_bounds__(256) void gemm_bt(const unsigned short* __restrict__ A,
                                               const unsigned short* __restrict__ Bt,
                                               unsigned short* __restrict__ Cq,
                                               unsigned short* __restrict__ Ck,
                                               unsigned short* __restrict__ Cv,
                                               float* __restrict__ Cf,
                                               int M, int N, int K, int mode){
  constexpr int MI = BM/32;                 // acc rows per wave (4 or 2)
  constexpr int ABUF = BM*64;               // shorts per A buffer
  constexpr int DBUFN = 2*ABUF + 2*8192;    // dbuf total shorts
  constexpr int SMEMN = (DBUFN > 17408) ? DBUFN : 17408;
  __shared__ __align__(16) unsigned short smem[SMEMN];
  const int t = threadIdx.x;
  const int w = t >> 6, lane = t & 63, l15 = lane & 15, quad = lane >> 4;

  // block swizzle: 8 m-blocks share one B-column tile AND one XCD (see header)
  int lin = blockIdx.y * gridDim.x + blockIdx.x;
  int gn = gridDim.x;
  int per = 8 * gn;
  int gid = lin / per, rem = lin % per;
  int j = rem / gn, nc = rem % gn;
  const int m0 = (gid*8 + j) * BM;
  const int n0 = nc * 128;

  const int wm = (w >> 1)*(BM/2), wn = (w & 1)*64;
  const int lr8 = lane >> 3;              // row within the wave's 8-row staging group
  const int gc8 = (lane & 7) ^ lr8;       // swizzled global chunk this lane fetches
  const int h7 = l15 & 7;
  f32x4 acc[MI][4] = {};

  // stage K-tile starting at k0 into buffer bb (async, no wait here)
  auto stage = [&](int k0, int bb){
    unsigned short* as = smem + bb*ABUF;
    unsigned short* bs = smem + 2*ABUF + bb*8192;
    for (int p = 0; p < BM/32; ++p){
      int rbase = p*32 + w*8;             // wave-uniform
      glds16(&A [(size_t)(m0 + rbase + lr8)*K + k0 + gc8*8], &as[rbase*64]);
    }
    for (int p = 0; p < 4; ++p){
      int rbase = p*32 + w*8;
      glds16(&Bt[(size_t)(n0 + rbase + lr8)*K + k0 + gc8*8], &bs[rbase*64]);
    }
  };

  const int NS = K >> 6;
  stage(0, 0);
  for (int ks = 0; ks < NS; ++ks){
    const int bb = ks & 1;
    __syncthreads();                      // drains vmcnt -> buf bb ready; prev compute done
    if (ks + 1 < NS) stage((ks+1)*64, bb ^ 1);   // async into other buffer
    const unsigned short* as = smem + bb*ABUF;
    const unsigned short* bs = smem + 2*ABUF + bb*8192;
    for (int kk = 0; kk < 2; ++kk){
      const int cs = (((kk<<2) + quad) ^ h7) * 8;
      sh8 aF[MI], bF[4];
      for (int i = 0; i < MI; ++i)
        aF[i] = *(const sh8*)&as[(wm + i*16 + l15)*64 + cs];
      for (int i = 0; i < 4; ++i)
        bF[i] = *(const sh8*)&bs[(wn + i*16 + l15)*64 + cs];
      for (int mi = 0; mi < MI; ++mi)
        for (int ni = 0; ni < 4; ++ni)
          acc[mi][ni] = __builtin_amdgcn_mfma_f32_16x16x32_bf16(aF[mi], bF[ni], acc[mi][ni], 0, 0, 0);
    }
  }

  // C/D layout: col = lane&15, row = quad*4 + r (m89/m91-verified)
  if (mode == 2){
    for (int mi = 0; mi < MI; ++mi){
      int rowb = m0 + wm + mi*16 + quad*4;
      for (int ni = 0; ni < 4; ++ni){
        int col = n0 + wn + ni*16 + l15;
        for (int r = 0; r < 4; ++r)
          Cf[(size_t)(rowb + r)*N + col] = acc[mi][ni][r];
      }
    }
    return;
  }

  if constexpr (BM == 128){
    // mode 0: LDS round-trip epilogue. Ct = 128x136 shorts aliases smem (dbuf dead now).
    __syncthreads();
    unsigned short* Ct = smem;
    const bool isv = (n0 >= 2048);
    const float cscale = (n0 < 1024) ? QSCALE : 1.0f;   // fold softmax scale into q
    for (int mi = 0; mi < 4; ++mi){
      for (int ni = 0; ni < 4; ++ni){
        for (int r = 0; r < 4; ++r){
          int lr = wm + mi*16 + quad*4 + r;   // local m (s) index
          int lc = wn + ni*16 + l15;          // local n (col) index
          unsigned short bv = f2bf(acc[mi][ni][r] * cscale);
          if (isv) Ct[lc*LDC + lr] = bv;      // transposed for V
          else     Ct[lr*LDC + lc] = bv;
        }
      }
    }
    __syncthreads();

    const int b = m0 >> 11, sbase = m0 & 2047;
    const int hbase = (n0 & 1023) >> 6;
    if (!isv){
      unsigned short* dst = (n0 < 1024) ? Cq : Ck;
      for (int i = 0; i < 8; ++i){
        int s  = i*16 + (t >> 4);
        int hh = (t >> 3) & 1;
        int c  = t & 7;
        uint4 val = *(const uint4*)&Ct[s*LDC + hh*64 + c*8];
        int h = hbase + hh;
        *(uint4*)&dst[((size_t)(b*16 + h)*2048 + sbase + s)*64 + c*8] = val;
      }
    } else {
      for (int i = 0; i < 8; ++i){
        int ecol = i*16 + (t >> 4);
        int s0   = (t & 15)*8;
        uint4 val = *(const uint4*)&Ct[ecol*LDC + s0];
        int hh = ecol >> 6, e = ecol & 63;
        int h = hbase + hh;
        *(uint4*)&Cv[((size_t)(b*16 + h)*64 + e)*2048 + sbase + s0] = val;
      }
    }
  }
}

// ---------------- flash attention, SPLIT-K over keys: 1024 blocks = 4 blocks/CU ----------------
// R9: grid was the occupancy binder (512 blocks = 2/CU, Occ 33%, VALU 47%). Each block
// now takes one 1024-key half (16 kt tiles): per-CU DMA/VALU/MFMA totals unchanged, but
// 4 blocks/CU = 32 waves/CU. No running-max in this softmax -> partials combine exactly:
// block writes numerator O (bf16) + l (f32); attn_reduce divides, applies query mask.
// LDS 34KB (permlane P-path, R3-verified; no Ps buffer) -> 4 blocks/CU fits (136KB).
__global__ __launch_bounds__(512) void flash_attn(const unsigned short* __restrict__ q,
                                                  const unsigned short* __restrict__ k,
                                                  const unsigned short* __restrict__ vt,
                                                  const int* __restrict__ mask,
                                                  unsigned short* __restrict__ O0,
                                                  unsigned short* __restrict__ O1,
                                                  float* __restrict__ l0,
                                                  float* __restrict__ l1){
  __shared__ __align__(16) unsigned short Ks[2][4096];   // [buf][64 key][64 e] xor-swizzled
  __shared__ __align__(16) unsigned short Vs[2][4096];   // [buf][64 e][64 key] xor-swizzled
  __shared__ __align__(16) unsigned short kmb[1024];     // bf16 key-mask adds for THIS half

  const int idx = blockIdx.x;
  const int xcd = idx & 7, sub = idx >> 3;    // sub 0..127
  const int bh = xcd*4 + (sub & 3);           // 4 (b,h) per XCD -> K/V L2-resident
  const int qrest = sub >> 2;                 // 0..31
  const int qt = qrest & 15;                  // q-tile 0..15
  const int half = qrest >> 4;                // key half 0..1
  const int hk0 = half << 10;                 // first key of this half
  const int b = bh >> 4, h = bh & 15;
  const int t = threadIdx.x;
  const int w = t >> 6, lane = t & 63, l15 = lane & 15, quad = lane >> 4;
  const size_t base = (size_t)bh * 2048 * 64;

  unsigned short* Op = half ? O1 : O0;
  float*          lp = half ? l1 : l0;

  // Q B-fragments for this wave's strip straight from global (q pre-scaled by QSCALE)
  const unsigned short* qp0 = q + base + (size_t)(qt*128 + w*16 + l15)*64;
  sh8 qf[2];
  qf[0] = *(const sh8*)(qp0 +      quad*8);
  qf[1] = *(const sh8*)(qp0 + 32 + quad*8);

  { // preload this half's key mask -> kmb bf16: 512 threads x 2 ints = 1024
    int2 mv = ((const int2*)(mask + b*2048 + hk0))[t];
    ((unsigned*)kmb)[t] = (mv.x ? 0u : (unsigned)KMBF16) | ((mv.y ? 0u : (unsigned)KMBF16) << 16);
  }

  const int lr8 = lane >> 3;              // staging row within 8-row group
  const int gc8 = (lane & 7) ^ lr8;       // swizzled global source chunk
  const int h7 = l15 & 7;
  const int cs0 = ((quad    ) ^ h7) * 8;  // kk=0 swizzled read chunk (K/V tiles)
  const int cs1 = ((quad + 4) ^ h7) * 8;  // kk=1

  // stage K/V tile kt (local to half) into buffer bb: wave w covers rows w*8..w*8+7
  auto stageKV = [&](int kt, int bb){
    int r0 = w*8;                         // wave-uniform LDS base row
    glds16(&k [base + (size_t)(hk0 + kt*64 + r0 + lr8)*64 + gc8*8], &Ks[bb][r0*64]);
    glds16(&vt[base + (size_t)(r0 + lr8)*2048 + hk0 + kt*64 + gc8*8], &Vs[bb][r0*64]);
  };

  float la[4] = {};
  f32x4 O[4] = {};   // O^T[et]: row=quad*4+r=e, col=l15=qrow

  stageKV(0, 0);
  for (int kt = 0; kt < 16; ++kt){
    const int bb = kt & 1;
    __syncthreads();                      // buf bb staged; prev compute done
    if (kt + 1 < 16) stageKV(kt + 1, bb ^ 1);   // async into other buffer

    // S^T = K·Q^T + km (mask folded into the MFMA C-init)
    unsigned ed[4][2];   // per mt: bf16 pairs (E0,E1),(E2,E3) -- keys mt*16+quad*4+{0..3}
    for (int mt = 0; mt < 4; ++mt){
      sh8 a0 = *(const sh8*)&Ks[bb][(mt*16 + l15)*64 + cs0];
      sh8 a1 = *(const sh8*)&Ks[bb][(mt*16 + l15)*64 + cs1];
      unsigned long long kq = *(const unsigned long long*)&kmb[kt*64 + mt*16 + quad*4];
      unsigned d0 = (unsigned)kq, d1 = (unsigned)(kq >> 32);
      f32x4 a;
      a[0] = __uint_as_float(d0 << 16);
      a[1] = __uint_as_float(d0 & 0xFFFF0000u);
      a[2] = __uint_as_float(d1 << 16);
      a[3] = __uint_as_float(d1 & 0xFFFF0000u);
      a = __builtin_amdgcn_mfma_f32_16x16x32_bf16(a0, qf[0], a, 0, 0, 0);
      a = __builtin_amdgcn_mfma_f32_16x16x32_bf16(a1, qf[1], a, 0, 0, 0);
      float e0 = EXP2F(a[0]); la[0] += e0;
      float e1 = EXP2F(a[1]); la[1] += e1;
      float e2 = EXP2F(a[2]); la[2] += e2;
      float e3 = EXP2F(a[3]); la[3] += e3;
      __hip_bfloat162 lo = __float22bfloat162_rn(make_float2(e0, e1));
      __hip_bfloat162 hi = __float22bfloat162_rn(make_float2(e2, e3));
      ed[mt][0] = *(unsigned*)&lo;
      ed[mt][1] = *(unsigned*)&hi;
    }

    // in-register P redistribution -> B-frags pf0 (keys 0..31), pf1 (keys 32..63).
    // p32swap then p16swap per (mt-pair g, dword d) -- R3-verified correct.
    union { unsigned u[8]; sh8 s[2]; } pf;
    #pragma unroll
    for (int g = 0; g < 2; ++g){
      #pragma unroll
      for (int d = 0; d < 2; ++d){
        unsigned A = ed[2*g][d], Bv = ed[2*g+1][d];
        pl32swap(A, Bv);
        pl16swap(A, Bv);
        pf.u[g*4 + d]     = A;
        pf.u[g*4 + d + 2] = Bv;
      }
    }
    sh8 pf0 = pf.s[0], pf1 = pf.s[1];

    // O^T += V^T · P (P in registers; V from LDS)
    #pragma unroll
    for (int et = 0; et < 4; ++et){
      sh8 vf0 = *(const sh8*)&Vs[bb][(et*16 + l15)*64 + cs0];
      O[et] = __builtin_amdgcn_mfma_f32_16x16x32_bf16(vf0, pf0, O[et], 0, 0, 0);
    }
    #pragma unroll
    for (int et = 0; et < 4; ++et){
      sh8 vf1 = *(const sh8*)&Vs[bb][(et*16 + l15)*64 + cs1];
      O[et] = __builtin_amdgcn_mfma_f32_16x16x32_bf16(vf1, pf1, O[et], 0, 0, 0);
    }
  }

  // epilogue: write partial numerator (bf16) + partial l (f32); division in attn_reduce
  {
    float l_i = (la[0] + la[1]) + (la[2] + la[3]);
    l_i += __shfl_xor(l_i, 16);
    l_i += __shfl_xor(l_i, 32);
    int srow = qt*128 + w*16 + l15;
    if (quad == 0) lp[(size_t)bh*2048 + srow] = l_i;
    unsigned short* crow = Op + (((size_t)b*2048 + srow)*16 + h)*64;
    for (int et = 0; et < 4; ++et)
      *(unsigned long long*)&crow[et*16 + quad*4] =
        pack4bf(O[et][0], O[et][1], O[et][2], O[et][3]);
  }
}

// ---------------- combine split-K halves: ctx = (O0+O1)/(l0+l1) * qry_mask ----------------
__global__ __launch_bounds__(256) void attn_reduce(const unsigned short* __restrict__ O0,
                                                   const unsigned short* __restrict__ O1,
                                                   const float* __restrict__ l0,
                                                   const float* __restrict__ l1,
                                                   const int* __restrict__ mask,
                                                   unsigned short* __restrict__ ctx){
  int gid = blockIdx.x*256 + threadIdx.x;        // 524288 threads x 8 bf16
  int h = (gid >> 3) & 15, s = (gid >> 7) & 2047, b = gid >> 18;
  size_t off = (size_t)gid * 8;
  union { uint4 v; unsigned u[4]; } ua, uc, ur;
  ua.v = *(const uint4*)&O0[off];
  uc.v = *(const uint4*)&O1[off];
  int li = (b*16 + h)*2048 + s;
  float l = l0[li] + l1[li];
  float inv = (mask[b*2048 + s] && l > 0.f) ? 1.f/l : 0.f;
  #pragma unroll
  for (int i = 0; i < 4; ++i){
    float e0 = (__uint_as_float(ua.u[i] << 16) + __uint_as_float(uc.u[i] << 16)) * inv;
    float e1 = (__uint_as_float(ua.u[i] & 0xFFFF0000u) + __uint_as_float(uc.u[i] & 0xFFFF0000u)) * inv;
    __hip_bfloat162 p = __float22bfloat162_rn(make_float2(e0, e1));
    ur.u[i] = *(unsigned*)&p;
  }
  *(uint4*)&ctx[off] = ur.v;
}

extern "C" void kernel_launch(void* const* d_in, const int* in_sizes, int n_in,
                              void* d_out, int out_size, void* d_ws, size_t ws_size,
                              hipStream_t stream){
  const float* x  = (const float*)d_in[0];
  const int* mask = (const int*)  d_in[1];
  const float* Wq = (const float*)d_in[2];
  const float* Wk = (const float*)d_in[3];
  const float* Wv = (const float*)d_in[4];
  const float* Wo = (const float*)d_in[5];
  float* out = (float*)d_out;

  char* ws = (char*)d_ws;                                  // total 48 MiB
  // region lifetimes:
  //  0-8   MiB: x_bf (cvt->gemm0), then Of0 partial numerator (flash->reduce)
  //  8-14  MiB: wt (transpose->gemm0), then l0/l1 f32 (flash->reduce, 512KB)
  //  14-16 MiB: wo_bf (cvt->gemm2)
  //  16-24 MiB: qb (gemm0->flash), then ctx (reduce->gemm2)
  //  24-32 MiB: kb (gemm0->flash)
  //  32-40 MiB: vtb (gemm0->flash)
  //  40-48 MiB: Of1 partial numerator (flash->reduce)
  unsigned short* x_bf  = (unsigned short*)(ws);
  unsigned short* wt    = (unsigned short*)(ws + 8388608);
  unsigned short* wo_bf = (unsigned short*)(ws + 14680064);
  unsigned short* qb    = (unsigned short*)(ws + 16777216);
  unsigned short* kb    = (unsigned short*)(ws + 25165824);
  unsigned short* vtb   = (unsigned short*)(ws + 33554432);
  unsigned short* Of0   = (unsigned short*)(ws);            // aliases x_bf (dead)
  float*          l0    = (float*)(ws + 8388608);           // aliases wt (dead)
  float*          l1    = (float*)(ws + 8388608 + 262144);
  unsigned short* Of1   = (unsigned short*)(ws + 41943040);
  unsigned short* ctx   = (unsigned short*)(ws + 16777216); // aliases qb (dead post-flash)

  cvt_bf16_2<<<5120, 256, 0, stream>>>(x, x_bf, 1048576, Wo, wo_bf, 262144);
  transpose_w<<<768, 256, 0, stream>>>(Wq, Wk, Wv, wt);
  gemm_bt<128><<<dim3(24, 32), 256, 0, stream>>>(x_bf, wt, qb, kb, vtb, nullptr, 4096, 3072, 1024, 0);
  flash_attn<<<1024, 512, 0, stream>>>(qb, kb, vtb, mask, Of0, Of1, l0, l1);
  attn_reduce<<<2048, 256, 0, stream>>>(Of0, Of1, l0, l1, mask, ctx);
  gemm_bt<64><<<dim3(8, 64), 256, 0, stream>>>(ctx, wo_bf, nullptr, nullptr, nullptr, out, 4096, 1024, 1024, 2);
}